// Round 1
// baseline (3441.283 us; speedup 1.0000x reference)
//
#include <hip/hip_runtime.h>

#define FDIM 64
#define NSDIM 64
#define TREP 3
#define EPSV 1e-8f

// ---------- helpers ----------
__device__ __forceinline__ float wsum(float v) {
#pragma unroll
  for (int o = 32; o > 0; o >>= 1) v += __shfl_xor(v, o);
  return v;
}

// ---------- row GEMM: out[r,:] = act(in[r,:]) @ W (+bias), W is (64,64) row-major ----------
template<bool RELU_IN, bool ADD_B>
__global__ void rowgemm_k(const float* __restrict__ in, const float* __restrict__ W,
                          const float* __restrict__ bias, float* __restrict__ out,
                          int rows)
{
  __shared__ float Wl[FDIM * FDIM];
  for (int i = threadIdx.x; i < FDIM * FDIM; i += blockDim.x) Wl[i] = W[i];
  __syncthreads();
  const int lane = threadIdx.x & 63;
  const int wib  = threadIdx.x >> 6;
  const int wpb  = blockDim.x >> 6;
  for (int row = blockIdx.x * wpb + wib; row < rows; row += gridDim.x * wpb) {
    float x = in[row * FDIM + lane];
    if (RELU_IN) x = fmaxf(x, 0.f);
    float acc = ADD_B ? bias[lane] : 0.f;
#pragma unroll
    for (int k = 0; k < FDIM; ++k)
      acc = fmaf(__shfl(x, k), Wl[k * FDIM + lane], acc);
    out[row * FDIM + lane] = acc;
  }
}

// ---------- row L2 norms ----------
__global__ void rownorm_k(const float* __restrict__ in, float* __restrict__ out, int rows)
{
  const int lane = threadIdx.x & 63;
  const int wib  = threadIdx.x >> 6;
  const int wpb  = blockDim.x >> 6;
  for (int row = blockIdx.x * wpb + wib; row < rows; row += gridDim.x * wpb) {
    float v = in[row * FDIM + lane];
    float s = wsum(v * v);
    if (lane == 0) out[row] = sqrtf(s);
  }
}

// ---------- per-edge mask + degree ----------
__global__ void edge_mask_deg_k(const int* __restrict__ src, const int* __restrict__ dst,
                                const float* __restrict__ f, const float* __restrict__ trans,
                                const float* __restrict__ normf, const float* __restrict__ normt,
                                unsigned* __restrict__ mask, float* __restrict__ deg,
                                int nE, int nN)
{
  const int lane = threadIdx.x & 63;
  const int wib  = threadIdx.x >> 6;
  const int wpb  = blockDim.x >> 6;
  for (int e = blockIdx.x * wpb + wib; e < nE; e += gridDim.x * wpb) {
    const int s = src[e], d = dst[e];
    const float fs = f[s * FDIM + lane];
    const float fd = f[d * FDIM + lane];
    float d0 = fs * fd;
    float d1 = trans[(0 * nN + s) * FDIM + lane] * fd;
    float d2 = trans[(1 * nN + s) * FDIM + lane] * fd;
    float d3 = trans[(2 * nN + s) * FDIM + lane] * fd;
#pragma unroll
    for (int o = 32; o > 0; o >>= 1) {
      d0 += __shfl_xor(d0, o);
      d1 += __shfl_xor(d1, o);
      d2 += __shfl_xor(d2, o);
      d3 += __shfl_xor(d3, o);
    }
    const float nfd = fmaxf(normf[d], EPSV);
    const float sim0 = d0 / (fmaxf(normf[s], EPSV) * nfd);
    unsigned m = 0;
    if (d1 / (fmaxf(normt[0 * nN + s], EPSV) * nfd) > sim0) m |= 1u;
    if (d2 / (fmaxf(normt[1 * nN + s], EPSV) * nfd) > sim0) m |= 2u;
    if (d3 / (fmaxf(normt[2 * nN + s], EPSV) * nfd) > sim0) m |= 4u;
    if (lane == 0) {
      mask[e] = m;
      atomicAdd(&deg[d], 1.f);
      if (m & 1u) atomicAdd(&deg[nN + d], 1.f);
      if (m & 2u) atomicAdd(&deg[2 * nN + d], 1.f);
      if (m & 4u) atomicAdd(&deg[3 * nN + d], 1.f);
    }
  }
}

// ---------- deg -> dinv in place ----------
__global__ void dinv_k(float* __restrict__ deg, int nN)
{
  int i = blockIdx.x * blockDim.x + threadIdx.x;
  int tot = 4 * nN;
  if (i < tot) {
    float base = (i < nN) ? 1.f : 2.f;  // block0: +self ; replicas: +identity edge +self
    deg[i] = 1.f / sqrtf(deg[i] + base);
  }
}

// ---------- edge scatter: acc[dst_block] += xw[src]*dinv0[src] ----------
__global__ void scatter_k(const int* __restrict__ src, const int* __restrict__ dst,
                          const unsigned* __restrict__ mask, const float* __restrict__ xw,
                          const float* __restrict__ dinv, float* __restrict__ acc,
                          int nE, int nN)
{
  const int lane = threadIdx.x & 63;
  const int wib  = threadIdx.x >> 6;
  const int wpb  = blockDim.x >> 6;
  for (int e = blockIdx.x * wpb + wib; e < nE; e += gridDim.x * wpb) {
    const int s = src[e], d = dst[e];
    const unsigned m = mask[e];
    const float val = xw[s * FDIM + lane] * dinv[s];
    atomicAdd(&acc[d * FDIM + lane], val);
    if (m & 1u) atomicAdd(&acc[(nN + d) * FDIM + lane], val);
    if (m & 2u) atomicAdd(&acc[(2 * nN + d) * FDIM + lane], val);
    if (m & 4u) atomicAdd(&acc[(3 * nN + d) * FDIM + lane], val);
  }
}

// ---------- GCN finish epilogue ----------
// block0:  out = acc*di0 + xw_b0[v]*di0^2 + b
// block t: out = acc*dit + xw_b0[v]*di0*dit + xw_self*dit^2 + b
// L0: xw has N rows (tiled input => self term = xw_b0[v]); else xw has 4N rows.
template<bool L0, bool RELU>
__global__ void finish_k(const float* __restrict__ acc, const float* __restrict__ xw,
                         const float* __restrict__ dinv, const float* __restrict__ bias,
                         float* __restrict__ out, int nN)
{
  const int lane = threadIdx.x & 63;
  const int wib  = threadIdx.x >> 6;
  const int wpb  = blockDim.x >> 6;
  const int rows = 4 * nN;
  for (int row = blockIdx.x * wpb + wib; row < rows; row += gridDim.x * wpb) {
    const int blk = row / nN;
    const int v   = row - blk * nN;
    const float a   = acc[row * FDIM + lane];
    const float di0 = dinv[v];
    const float xb0 = xw[v * FDIM + lane];
    float res;
    if (blk == 0) {
      res = a * di0 + xb0 * di0 * di0;
    } else {
      const float dit  = dinv[blk * nN + v];
      const float self = L0 ? xb0 : xw[row * FDIM + lane];
      res = a * dit + xb0 * di0 * dit + self * dit * dit;
    }
    res += bias[lane];
    if (RELU) res = fmaxf(res, 0.f);
    out[row * FDIM + lane] = res;
  }
}

// ---------- logits + argmax + H accumulation ----------
__global__ void logits_argmax_k(const float* __restrict__ x2, const float* __restrict__ W,
                                const float* __restrict__ bias, float* __restrict__ H,
                                int nN)
{
  __shared__ float Wl[FDIM * NSDIM];
  for (int i = threadIdx.x; i < FDIM * NSDIM; i += blockDim.x) Wl[i] = W[i];
  __syncthreads();
  const int lane = threadIdx.x & 63;
  const int wib  = threadIdx.x >> 6;
  const int wpb  = blockDim.x >> 6;
  const int rows = 4 * nN;
  for (int row = blockIdx.x * wpb + wib; row < rows; row += gridDim.x * wpb) {
    float h = fmaxf(x2[row * FDIM + lane], 0.f);
    float acc = bias[lane];
#pragma unroll
    for (int k = 0; k < FDIM; ++k)
      acc = fmaf(__shfl(h, k), Wl[k * NSDIM + lane], acc);
    // argmax, first-index tiebreak (matches jnp.argmax)
    float bv = acc; int bi = lane;
#pragma unroll
    for (int o = 32; o > 0; o >>= 1) {
      float ov = __shfl_xor(bv, o);
      int   oi = __shfl_xor(bi, o);
      if (ov > bv || (ov == bv && oi < bi)) { bv = ov; bi = oi; }
    }
    if (lane == 0) {
      int v = row % nN;
      atomicAdd(&H[v * NSDIM + bi], 1.f);
    }
  }
}

// ---------- hyper[j,:] += x2_b0[i,:] where H[i,j] > 0 ----------
__global__ void hyper_k(const float* __restrict__ H, const float* __restrict__ x2,
                        float* __restrict__ hyper, int nN)
{
  const int lane = threadIdx.x & 63;
  const int wib  = threadIdx.x >> 6;
  const int wpb  = blockDim.x >> 6;
  for (int i = blockIdx.x * wpb + wib; i < nN; i += gridDim.x * wpb) {
    float hv = H[i * NSDIM + lane];
    unsigned long long ball = __ballot(hv > 0.f);
    float x = x2[i * FDIM + lane];
    while (ball) {
      int j = __ffsll((unsigned long long)ball) - 1;
      ball &= ball - 1;
      atomicAdd(&hyper[j * FDIM + lane], x);
    }
  }
}

__global__ void copy_k(const float* __restrict__ in, float* __restrict__ out, int n)
{
  int i = blockIdx.x * blockDim.x + threadIdx.x;
  if (i < n) out[i] = in[i];
}

// ---------- per-column histogram -> max + softmax denominator (H in {0..4}) ----------
__global__ void colstats_k(const float* __restrict__ H, float* __restrict__ cmax,
                           float* __restrict__ cden, int nN)
{
  __shared__ int s[8];
  const int j = blockIdx.x;
  if (threadIdx.x < 8) s[threadIdx.x] = 0;
  __syncthreads();
  int c[5] = {0, 0, 0, 0, 0};
  for (int i = threadIdx.x; i < nN; i += blockDim.x) {
    int v = (int)H[i * NSDIM + j];
    c[v]++;
  }
#pragma unroll
  for (int k = 0; k < 5; ++k) atomicAdd(&s[k], c[k]);
  __syncthreads();
  if (threadIdx.x == 0) {
    int m = 0;
#pragma unroll
    for (int k = 0; k < 5; ++k) if (s[k] > 0) m = k;
    float den = 0.f;
#pragma unroll
    for (int k = 0; k < 5; ++k) den += (float)s[k] * expf((float)(k - m));
    cmax[j] = (float)m;
    cden[j] = den;
  }
}

__global__ void hsoft_k(const float* __restrict__ H, const float* __restrict__ cmax,
                        const float* __restrict__ cden, float* __restrict__ out0, int nN)
{
  int idx = blockIdx.x * blockDim.x + threadIdx.x;
  int tot = nN * NSDIM;
  if (idx < tot) {
    int j = idx & (NSDIM - 1);
    out0[idx] = expf(H[idx] - cmax[j]) / cden[j];
  }
}

// ---------- dots = (features @ hyper^T) * 0.125, tiled 4x ----------
__global__ void dots_k(const float* __restrict__ f, const float* __restrict__ hyper,
                       float* __restrict__ out2, int nN)
{
  __shared__ float Ht[FDIM * NSDIM];  // transposed: Ht[k*NS + j] = hyper[j*F + k]
  for (int idx = threadIdx.x; idx < NSDIM * FDIM; idx += blockDim.x) {
    int j = idx / FDIM, k = idx - j * FDIM;
    Ht[k * NSDIM + j] = hyper[idx];
  }
  __syncthreads();
  const int lane = threadIdx.x & 63;
  const int wib  = threadIdx.x >> 6;
  const int wpb  = blockDim.x >> 6;
  for (int i = blockIdx.x * wpb + wib; i < nN; i += gridDim.x * wpb) {
    float fv = f[i * FDIM + lane];
    float acc = 0.f;
#pragma unroll
    for (int k = 0; k < FDIM; ++k)
      acc = fmaf(__shfl(fv, k), Ht[k * NSDIM + lane], acc);
    acc *= 0.125f;  // 64^-0.5
#pragma unroll
    for (int b = 0; b < 4; ++b)
      out2[(b * nN + i) * NSDIM + lane] = acc;
  }
}

// ---------- host ----------
extern "C" void kernel_launch(void* const* d_in, const int* in_sizes, int n_in,
                              void* d_out, int out_size, void* d_ws, size_t ws_size,
                              hipStream_t stream)
{
  const int* edge_index = (const int*)d_in[0];
  const float* features = (const float*)d_in[1];
  const float* W_lin    = (const float*)d_in[2];
  const float* b_lin    = (const float*)d_in[3];
  const float* gcn0_W   = (const float*)d_in[4];
  const float* gcn0_b   = (const float*)d_in[5];
  const float* gcn1_W   = (const float*)d_in[6];
  const float* gcn1_b   = (const float*)d_in[7];
  const float* lin1_W   = (const float*)d_in[8];
  const float* lin1_b   = (const float*)d_in[9];

  const int E = in_sizes[0] / 2;
  const int N = in_sizes[1] / FDIM;

  const int* src = edge_index;
  const int* dst = edge_index + E;

  // workspace layout
  float* ws    = (float*)d_ws;
  float* trans = ws;                       // T*N*F
  float* normf = trans + (size_t)TREP * N * FDIM;  // N
  float* normt = normf + N;                // T*N
  float* deg   = normt + (size_t)TREP * N; // 4N (becomes dinv in place)
  unsigned* mask = (unsigned*)(deg + (size_t)4 * N);  // E
  float* xw0  = (float*)(mask + E);        // N*F
  float* bufA = xw0 + (size_t)N * FDIM;    // 4N*F  (acc0 -> x1 -> acc1 -> x2)
  float* bufB = bufA + (size_t)4 * N * FDIM; // 4N*F (xw1)
  float* Harr = bufB + (size_t)4 * N * FDIM; // N*NS
  float* hyper = Harr + (size_t)N * NSDIM;   // NS*F
  float* cmax = hyper + NSDIM * FDIM;      // NS
  float* cden = cmax + NSDIM;              // NS

  float* out0 = (float*)d_out;             // H_soft (N,NS)
  float* out1 = out0 + (size_t)N * NSDIM;  // hyper (NS,F)
  float* out2 = out1 + NSDIM * FDIM;       // dots (4N,NS)

  const int BLK = 256;
  const int WPB = BLK / 64;
  auto wgrid = [](int items, int wpb) { return (items + wpb - 1) / wpb; };

  // zero accumulators
  hipMemsetAsync(deg, 0, (size_t)4 * N * sizeof(float), stream);
  hipMemsetAsync(Harr, 0, (size_t)N * NSDIM * sizeof(float), stream);
  hipMemsetAsync(hyper, 0, (size_t)NSDIM * FDIM * sizeof(float), stream);

  // 1) trans[t] = features @ W_lin[t] + b_lin[t]
  for (int t = 0; t < TREP; ++t)
    rowgemm_k<false, true><<<wgrid(N, WPB), BLK, 0, stream>>>(
        features, W_lin + (size_t)t * FDIM * FDIM, b_lin + (size_t)t * FDIM,
        trans + (size_t)t * N * FDIM, N);

  // 2) norms
  rownorm_k<<<wgrid(N, WPB), BLK, 0, stream>>>(features, normf, N);
  rownorm_k<<<wgrid(TREP * N, WPB), BLK, 0, stream>>>(trans, normt, TREP * N);

  // 3) edge mask + degrees
  edge_mask_deg_k<<<wgrid(E, WPB), BLK, 0, stream>>>(src, dst, features, trans,
                                                     normf, normt, mask, deg, E, N);

  // 4) dinv
  dinv_k<<<(4 * N + BLK - 1) / BLK, BLK, 0, stream>>>(deg, N);

  // 5) xw0 = relu(features) @ gcn0_W
  rowgemm_k<true, false><<<wgrid(N, WPB), BLK, 0, stream>>>(features, gcn0_W, nullptr, xw0, N);

  // 6) gcn0 scatter + finish -> x1 (relu'd) in bufA
  hipMemsetAsync(bufA, 0, (size_t)4 * N * FDIM * sizeof(float), stream);
  scatter_k<<<wgrid(E, WPB), BLK, 0, stream>>>(src, dst, mask, xw0, deg, bufA, E, N);
  finish_k<true, true><<<wgrid(4 * N, WPB), BLK, 0, stream>>>(bufA, xw0, deg, gcn0_b, bufA, N);

  // 7) xw1 = x1 @ gcn1_W (all 4N rows)
  rowgemm_k<false, false><<<wgrid(4 * N, WPB), BLK, 0, stream>>>(bufA, gcn1_W, nullptr, bufB, 4 * N);

  // 8) gcn1 scatter + finish -> x2 in bufA (no relu)
  hipMemsetAsync(bufA, 0, (size_t)4 * N * FDIM * sizeof(float), stream);
  scatter_k<<<wgrid(E, WPB), BLK, 0, stream>>>(src, dst, mask, bufB, deg, bufA, E, N);
  finish_k<false, false><<<wgrid(4 * N, WPB), BLK, 0, stream>>>(bufA, bufB, deg, gcn1_b, bufA, N);

  // 9) logits + argmax -> H counts
  logits_argmax_k<<<wgrid(4 * N, WPB), BLK, 0, stream>>>(bufA, lin1_W, lin1_b, Harr, N);

  // 10) hyper
  hyper_k<<<wgrid(N, WPB), BLK, 0, stream>>>(Harr, bufA, hyper, N);
  copy_k<<<(NSDIM * FDIM + BLK - 1) / BLK, BLK, 0, stream>>>(hyper, out1, NSDIM * FDIM);

  // 11) H softmax over axis 0
  colstats_k<<<NSDIM, BLK, 0, stream>>>(Harr, cmax, cden, N);
  hsoft_k<<<(N * NSDIM + BLK - 1) / BLK, BLK, 0, stream>>>(Harr, cmax, cden, out0, N);

  // 12) dots (computed once, written 4x)
  dots_k<<<wgrid(N, WPB), BLK, 0, stream>>>(features, hyper, out2, N);
}

// Round 2
// 2278.257 us; speedup vs baseline: 1.5105x; 1.5105x over previous
//
#include <hip/hip_runtime.h>

#define FDIM 64
#define NSDIM 64
#define TREP 3
#define EPSV 1e-8f

// ---------- helpers ----------
__device__ __forceinline__ float wsum(float v) {
#pragma unroll
  for (int o = 32; o > 0; o >>= 1) v += __shfl_xor(v, o);
  return v;
}

// ---------- row GEMM: out[r,:] = act(in[r,:]) @ W (+bias), W is (64,64) row-major ----------
template<bool RELU_IN, bool ADD_B>
__global__ void rowgemm_k(const float* __restrict__ in, const float* __restrict__ W,
                          const float* __restrict__ bias, float* __restrict__ out,
                          int rows)
{
  __shared__ float Wl[FDIM * FDIM];
  for (int i = threadIdx.x; i < FDIM * FDIM; i += blockDim.x) Wl[i] = W[i];
  __syncthreads();
  const int lane = threadIdx.x & 63;
  const int wib  = threadIdx.x >> 6;
  const int wpb  = blockDim.x >> 6;
  for (int row = blockIdx.x * wpb + wib; row < rows; row += gridDim.x * wpb) {
    float x = in[row * FDIM + lane];
    if (RELU_IN) x = fmaxf(x, 0.f);
    float acc = ADD_B ? bias[lane] : 0.f;
#pragma unroll
    for (int k = 0; k < FDIM; ++k)
      acc = fmaf(__shfl(x, k), Wl[k * FDIM + lane], acc);
    out[row * FDIM + lane] = acc;
  }
}

// ---------- row L2 norms ----------
__global__ void rownorm_k(const float* __restrict__ in, float* __restrict__ out, int rows)
{
  const int lane = threadIdx.x & 63;
  const int wib  = threadIdx.x >> 6;
  const int wpb  = blockDim.x >> 6;
  for (int row = blockIdx.x * wpb + wib; row < rows; row += gridDim.x * wpb) {
    float v = in[row * FDIM + lane];
    float s = wsum(v * v);
    if (lane == 0) out[row] = sqrtf(s);
  }
}

// ---------- per-edge mask + degree ----------
__global__ void edge_mask_deg_k(const int* __restrict__ src, const int* __restrict__ dst,
                                const float* __restrict__ f, const float* __restrict__ trans,
                                const float* __restrict__ normf, const float* __restrict__ normt,
                                unsigned* __restrict__ mask, float* __restrict__ deg,
                                int nE, int nN)
{
  const int lane = threadIdx.x & 63;
  const int wib  = threadIdx.x >> 6;
  const int wpb  = blockDim.x >> 6;
  for (int e = blockIdx.x * wpb + wib; e < nE; e += gridDim.x * wpb) {
    const int s = src[e], d = dst[e];
    const float fs = f[s * FDIM + lane];
    const float fd = f[d * FDIM + lane];
    float d0 = fs * fd;
    float d1 = trans[(0 * nN + s) * FDIM + lane] * fd;
    float d2 = trans[(1 * nN + s) * FDIM + lane] * fd;
    float d3 = trans[(2 * nN + s) * FDIM + lane] * fd;
#pragma unroll
    for (int o = 32; o > 0; o >>= 1) {
      d0 += __shfl_xor(d0, o);
      d1 += __shfl_xor(d1, o);
      d2 += __shfl_xor(d2, o);
      d3 += __shfl_xor(d3, o);
    }
    const float nfd = fmaxf(normf[d], EPSV);
    const float sim0 = d0 / (fmaxf(normf[s], EPSV) * nfd);
    unsigned m = 0;
    if (d1 / (fmaxf(normt[0 * nN + s], EPSV) * nfd) > sim0) m |= 1u;
    if (d2 / (fmaxf(normt[1 * nN + s], EPSV) * nfd) > sim0) m |= 2u;
    if (d3 / (fmaxf(normt[2 * nN + s], EPSV) * nfd) > sim0) m |= 4u;
    if (lane == 0) {
      mask[e] = m;
      atomicAdd(&deg[d], 1.f);
      if (m & 1u) atomicAdd(&deg[nN + d], 1.f);
      if (m & 2u) atomicAdd(&deg[2 * nN + d], 1.f);
      if (m & 4u) atomicAdd(&deg[3 * nN + d], 1.f);
    }
  }
}

// ---------- deg -> dinv in place ----------
__global__ void dinv_k(float* __restrict__ deg, int nN)
{
  int i = blockIdx.x * blockDim.x + threadIdx.x;
  int tot = 4 * nN;
  if (i < tot) {
    float base = (i < nN) ? 1.f : 2.f;  // block0: +self ; replicas: +identity edge +self
    deg[i] = 1.f / sqrtf(deg[i] + base);
  }
}

// ---------- edge scatter: acc[dst_block] += xw[src]*dinv0[src] ----------
__global__ void scatter_k(const int* __restrict__ src, const int* __restrict__ dst,
                          const unsigned* __restrict__ mask, const float* __restrict__ xw,
                          const float* __restrict__ dinv, float* __restrict__ acc,
                          int nE, int nN)
{
  const int lane = threadIdx.x & 63;
  const int wib  = threadIdx.x >> 6;
  const int wpb  = blockDim.x >> 6;
  for (int e = blockIdx.x * wpb + wib; e < nE; e += gridDim.x * wpb) {
    const int s = src[e], d = dst[e];
    const unsigned m = mask[e];
    const float val = xw[s * FDIM + lane] * dinv[s];
    atomicAdd(&acc[d * FDIM + lane], val);
    if (m & 1u) atomicAdd(&acc[(nN + d) * FDIM + lane], val);
    if (m & 2u) atomicAdd(&acc[(2 * nN + d) * FDIM + lane], val);
    if (m & 4u) atomicAdd(&acc[(3 * nN + d) * FDIM + lane], val);
  }
}

// ---------- GCN finish epilogue ----------
template<bool L0, bool RELU>
__global__ void finish_k(const float* __restrict__ acc, const float* __restrict__ xw,
                         const float* __restrict__ dinv, const float* __restrict__ bias,
                         float* __restrict__ out, int nN)
{
  const int lane = threadIdx.x & 63;
  const int wib  = threadIdx.x >> 6;
  const int wpb  = blockDim.x >> 6;
  const int rows = 4 * nN;
  for (int row = blockIdx.x * wpb + wib; row < rows; row += gridDim.x * wpb) {
    const int blk = row / nN;
    const int v   = row - blk * nN;
    const float a   = acc[row * FDIM + lane];
    const float di0 = dinv[v];
    const float xb0 = xw[v * FDIM + lane];
    float res;
    if (blk == 0) {
      res = a * di0 + xb0 * di0 * di0;
    } else {
      const float dit  = dinv[blk * nN + v];
      const float self = L0 ? xb0 : xw[row * FDIM + lane];
      res = a * dit + xb0 * di0 * dit + self * dit * dit;
    }
    res += bias[lane];
    if (RELU) res = fmaxf(res, 0.f);
    out[row * FDIM + lane] = res;
  }
}

// ---------- logits + argmax + H accumulation ----------
__global__ void logits_argmax_k(const float* __restrict__ x2, const float* __restrict__ W,
                                const float* __restrict__ bias, float* __restrict__ H,
                                int nN)
{
  __shared__ float Wl[FDIM * NSDIM];
  for (int i = threadIdx.x; i < FDIM * NSDIM; i += blockDim.x) Wl[i] = W[i];
  __syncthreads();
  const int lane = threadIdx.x & 63;
  const int wib  = threadIdx.x >> 6;
  const int wpb  = blockDim.x >> 6;
  const int rows = 4 * nN;
  for (int row = blockIdx.x * wpb + wib; row < rows; row += gridDim.x * wpb) {
    float h = fmaxf(x2[row * FDIM + lane], 0.f);
    float acc = bias[lane];
#pragma unroll
    for (int k = 0; k < FDIM; ++k)
      acc = fmaf(__shfl(h, k), Wl[k * NSDIM + lane], acc);
    float bv = acc; int bi = lane;
#pragma unroll
    for (int o = 32; o > 0; o >>= 1) {
      float ov = __shfl_xor(bv, o);
      int   oi = __shfl_xor(bi, o);
      if (ov > bv || (ov == bv && oi < bi)) { bv = ov; bi = oi; }
    }
    if (lane == 0) {
      int v = row % nN;
      atomicAdd(&H[v * NSDIM + bi], 1.f);
    }
  }
}

// ---------- hyper[j,:] += x2_b0[i,:] where H[i,j] > 0 ----------
// LDS-accumulated: per-block 64x64 LDS tile, one coalesced atomic flush per block.
__global__ void hyper_k(const float* __restrict__ H, const float* __restrict__ x2,
                        float* __restrict__ hyper, int nN)
{
  __shared__ float hl[NSDIM * FDIM];
  for (int i = threadIdx.x; i < NSDIM * FDIM; i += blockDim.x) hl[i] = 0.f;
  __syncthreads();
  const int lane = threadIdx.x & 63;
  const int wib  = threadIdx.x >> 6;
  const int wpb  = blockDim.x >> 6;
  for (int i = blockIdx.x * wpb + wib; i < nN; i += gridDim.x * wpb) {
    float hv = H[i * NSDIM + lane];
    unsigned long long ball = __ballot(hv > 0.f);
    float x = x2[i * FDIM + lane];
    while (ball) {
      int j = __ffsll((unsigned long long)ball) - 1;
      ball &= ball - 1;
      atomicAdd(&hl[j * FDIM + lane], x);   // LDS atomic, conflict-free lanes
    }
  }
  __syncthreads();
  for (int i = threadIdx.x; i < NSDIM * FDIM; i += blockDim.x) {
    float v = hl[i];
    if (v != 0.f) atomicAdd(&hyper[i], v);
  }
}

__global__ void copy_k(const float* __restrict__ in, float* __restrict__ out, int n)
{
  int i = blockIdx.x * blockDim.x + threadIdx.x;
  if (i < n) out[i] = in[i];
}

// ---------- per-column histogram -> max + softmax denominator (H in {0..4}) ----------
__global__ void colstats_k(const float* __restrict__ H, float* __restrict__ cmax,
                           float* __restrict__ cden, int nN)
{
  __shared__ int s[8];
  const int j = blockIdx.x;
  if (threadIdx.x < 8) s[threadIdx.x] = 0;
  __syncthreads();
  int c[5] = {0, 0, 0, 0, 0};
  for (int i = threadIdx.x; i < nN; i += blockDim.x) {
    int v = (int)H[i * NSDIM + j];
    c[v]++;
  }
#pragma unroll
  for (int k = 0; k < 5; ++k) atomicAdd(&s[k], c[k]);
  __syncthreads();
  if (threadIdx.x == 0) {
    int m = 0;
#pragma unroll
    for (int k = 0; k < 5; ++k) if (s[k] > 0) m = k;
    float den = 0.f;
#pragma unroll
    for (int k = 0; k < 5; ++k) den += (float)s[k] * expf((float)(k - m));
    cmax[j] = (float)m;
    cden[j] = den;
  }
}

__global__ void hsoft_k(const float* __restrict__ H, const float* __restrict__ cmax,
                        const float* __restrict__ cden, float* __restrict__ out0, int nN)
{
  int idx = blockIdx.x * blockDim.x + threadIdx.x;
  int tot = nN * NSDIM;
  if (idx < tot) {
    int j = idx & (NSDIM - 1);
    out0[idx] = expf(H[idx] - cmax[j]) / cden[j];
  }
}

// ---------- dots = (features @ hyper^T) * 0.125, tiled 4x ----------
__global__ void dots_k(const float* __restrict__ f, const float* __restrict__ hyper,
                       float* __restrict__ out2, int nN)
{
  __shared__ float Ht[FDIM * NSDIM];  // transposed: Ht[k*NS + j] = hyper[j*F + k]
  for (int idx = threadIdx.x; idx < NSDIM * FDIM; idx += blockDim.x) {
    int j = idx / FDIM, k = idx - j * FDIM;
    Ht[k * NSDIM + j] = hyper[idx];
  }
  __syncthreads();
  const int lane = threadIdx.x & 63;
  const int wib  = threadIdx.x >> 6;
  const int wpb  = blockDim.x >> 6;
  for (int i = blockIdx.x * wpb + wib; i < nN; i += gridDim.x * wpb) {
    float fv = f[i * FDIM + lane];
    float acc = 0.f;
#pragma unroll
    for (int k = 0; k < FDIM; ++k)
      acc = fmaf(__shfl(fv, k), Ht[k * NSDIM + lane], acc);
    acc *= 0.125f;  // 64^-0.5
#pragma unroll
    for (int b = 0; b < 4; ++b)
      out2[(b * nN + i) * NSDIM + lane] = acc;
  }
}

// ---------- host ----------
extern "C" void kernel_launch(void* const* d_in, const int* in_sizes, int n_in,
                              void* d_out, int out_size, void* d_ws, size_t ws_size,
                              hipStream_t stream)
{
  const int* edge_index = (const int*)d_in[0];
  const float* features = (const float*)d_in[1];
  const float* W_lin    = (const float*)d_in[2];
  const float* b_lin    = (const float*)d_in[3];
  const float* gcn0_W   = (const float*)d_in[4];
  const float* gcn0_b   = (const float*)d_in[5];
  const float* gcn1_W   = (const float*)d_in[6];
  const float* gcn1_b   = (const float*)d_in[7];
  const float* lin1_W   = (const float*)d_in[8];
  const float* lin1_b   = (const float*)d_in[9];

  const int E = in_sizes[0] / 2;
  const int N = in_sizes[1] / FDIM;

  const int* src = edge_index;
  const int* dst = edge_index + E;

  // workspace layout
  float* ws    = (float*)d_ws;
  float* trans = ws;                       // T*N*F
  float* normf = trans + (size_t)TREP * N * FDIM;  // N
  float* normt = normf + N;                // T*N
  float* deg   = normt + (size_t)TREP * N; // 4N (becomes dinv in place)
  unsigned* mask = (unsigned*)(deg + (size_t)4 * N);  // E
  float* xw0  = (float*)(mask + E);        // N*F
  float* bufA = xw0 + (size_t)N * FDIM;    // 4N*F  (acc0 -> x1 -> acc1 -> x2)
  float* bufB = bufA + (size_t)4 * N * FDIM; // 4N*F (xw1)
  float* Harr = bufB + (size_t)4 * N * FDIM; // N*NS
  float* hyper = Harr + (size_t)N * NSDIM;   // NS*F
  float* cmax = hyper + NSDIM * FDIM;      // NS
  float* cden = cmax + NSDIM;              // NS

  float* out0 = (float*)d_out;             // H_soft (N,NS)
  float* out1 = out0 + (size_t)N * NSDIM;  // hyper (NS,F)
  float* out2 = out1 + NSDIM * FDIM;       // dots (4N,NS)

  const int BLK = 256;
  const int WPB = BLK / 64;
  auto wgrid = [](int items, int wpb) { return (items + wpb - 1) / wpb; };

  // zero accumulators
  hipMemsetAsync(deg, 0, (size_t)4 * N * sizeof(float), stream);
  hipMemsetAsync(Harr, 0, (size_t)N * NSDIM * sizeof(float), stream);
  hipMemsetAsync(hyper, 0, (size_t)NSDIM * FDIM * sizeof(float), stream);

  // 1) trans[t] = features @ W_lin[t] + b_lin[t]
  for (int t = 0; t < TREP; ++t)
    rowgemm_k<false, true><<<wgrid(N, WPB), BLK, 0, stream>>>(
        features, W_lin + (size_t)t * FDIM * FDIM, b_lin + (size_t)t * FDIM,
        trans + (size_t)t * N * FDIM, N);

  // 2) norms
  rownorm_k<<<wgrid(N, WPB), BLK, 0, stream>>>(features, normf, N);
  rownorm_k<<<wgrid(TREP * N, WPB), BLK, 0, stream>>>(trans, normt, TREP * N);

  // 3) edge mask + degrees
  edge_mask_deg_k<<<wgrid(E, WPB), BLK, 0, stream>>>(src, dst, features, trans,
                                                     normf, normt, mask, deg, E, N);

  // 4) dinv
  dinv_k<<<(4 * N + BLK - 1) / BLK, BLK, 0, stream>>>(deg, N);

  // 5) xw0 = relu(features) @ gcn0_W
  rowgemm_k<true, false><<<wgrid(N, WPB), BLK, 0, stream>>>(features, gcn0_W, nullptr, xw0, N);

  // 6) gcn0 scatter + finish -> x1 (relu'd) in bufA
  hipMemsetAsync(bufA, 0, (size_t)4 * N * FDIM * sizeof(float), stream);
  scatter_k<<<wgrid(E, WPB), BLK, 0, stream>>>(src, dst, mask, xw0, deg, bufA, E, N);
  finish_k<true, true><<<wgrid(4 * N, WPB), BLK, 0, stream>>>(bufA, xw0, deg, gcn0_b, bufA, N);

  // 7) xw1 = x1 @ gcn1_W (all 4N rows)
  rowgemm_k<false, false><<<wgrid(4 * N, WPB), BLK, 0, stream>>>(bufA, gcn1_W, nullptr, bufB, 4 * N);

  // 8) gcn1 scatter + finish -> x2 in bufA (no relu)
  hipMemsetAsync(bufA, 0, (size_t)4 * N * FDIM * sizeof(float), stream);
  scatter_k<<<wgrid(E, WPB), BLK, 0, stream>>>(src, dst, mask, bufB, deg, bufA, E, N);
  finish_k<false, false><<<wgrid(4 * N, WPB), BLK, 0, stream>>>(bufA, bufB, deg, gcn1_b, bufA, N);

  // 9) logits + argmax -> H counts
  logits_argmax_k<<<wgrid(4 * N, WPB), BLK, 0, stream>>>(bufA, lin1_W, lin1_b, Harr, N);

  // 10) hyper (LDS-accumulated, 128 blocks)
  hyper_k<<<128, BLK, 0, stream>>>(Harr, bufA, hyper, N);
  copy_k<<<(NSDIM * FDIM + BLK - 1) / BLK, BLK, 0, stream>>>(hyper, out1, NSDIM * FDIM);

  // 11) H softmax over axis 0
  colstats_k<<<NSDIM, BLK, 0, stream>>>(Harr, cmax, cden, N);
  hsoft_k<<<(N * NSDIM + BLK - 1) / BLK, BLK, 0, stream>>>(Harr, cmax, cden, out0, N);

  // 12) dots (computed once, written 4x)
  dots_k<<<wgrid(N, WPB), BLK, 0, stream>>>(features, hyper, out2, N);
}

// Round 3
// 1658.275 us; speedup vs baseline: 2.0752x; 1.3739x over previous
//
#include <hip/hip_runtime.h>

#define FDIM 64
#define NSDIM 64
#define TREP 3
#define EPSV 1e-8f

// ---------- helpers ----------
__device__ __forceinline__ float wsum(float v) {
#pragma unroll
  for (int o = 32; o > 0; o >>= 1) v += __shfl_xor(v, o);
  return v;
}

// ---------- batched row GEMM for trans: out[t,r,:] = in[r,:] @ W[t] + b[t] ----------
__global__ void trans_gemm_k(const float* __restrict__ in, const float* __restrict__ W,
                             const float* __restrict__ bias, float* __restrict__ out,
                             int rows)
{
  const int t = blockIdx.y;
  __shared__ float Wl[FDIM * FDIM];
  for (int i = threadIdx.x; i < FDIM * FDIM; i += blockDim.x)
    Wl[i] = W[t * FDIM * FDIM + i];
  __syncthreads();
  const int lane = threadIdx.x & 63;
  const int wib  = threadIdx.x >> 6;
  const int wpb  = blockDim.x >> 6;
  const float b = bias[t * FDIM + lane];
  for (int row = blockIdx.x * wpb + wib; row < rows; row += gridDim.x * wpb) {
    float x = in[row * FDIM + lane];
    float acc = b;
#pragma unroll
    for (int k = 0; k < FDIM; ++k)
      acc = fmaf(__shfl(x, k), Wl[k * FDIM + lane], acc);
    out[((size_t)t * rows + row) * FDIM + lane] = acc;
  }
}

// ---------- row GEMM: out[r,:] = act(in[r,:]) @ W, W is (64,64) row-major ----------
template<bool RELU_IN>
__global__ void rowgemm_k(const float* __restrict__ in, const float* __restrict__ W,
                          float* __restrict__ out, int rows)
{
  __shared__ float Wl[FDIM * FDIM];
  for (int i = threadIdx.x; i < FDIM * FDIM; i += blockDim.x) Wl[i] = W[i];
  __syncthreads();
  const int lane = threadIdx.x & 63;
  const int wib  = threadIdx.x >> 6;
  const int wpb  = blockDim.x >> 6;
  for (int row = blockIdx.x * wpb + wib; row < rows; row += gridDim.x * wpb) {
    float x = in[row * FDIM + lane];
    if (RELU_IN) x = fmaxf(x, 0.f);
    float acc = 0.f;
#pragma unroll
    for (int k = 0; k < FDIM; ++k)
      acc = fmaf(__shfl(x, k), Wl[k * FDIM + lane], acc);
    out[row * FDIM + lane] = acc;
  }
}

// ---------- row L2 norms ----------
__global__ void rownorm_k(const float* __restrict__ in, float* __restrict__ out, int rows)
{
  const int lane = threadIdx.x & 63;
  const int wib  = threadIdx.x >> 6;
  const int wpb  = blockDim.x >> 6;
  for (int row = blockIdx.x * wpb + wib; row < rows; row += gridDim.x * wpb) {
    float v = in[row * FDIM + lane];
    float s = wsum(v * v);
    if (lane == 0) out[row] = fmaxf(sqrtf(s), EPSV);
  }
}

// ---------- per-edge mask + int degree counts ----------
// cross-multiplied compare: sim_t > sim0  <=>  d_t * nf_s > d0 * nt_t  (norms > 0)
__global__ void edge_mask_cnt_k(const int* __restrict__ src, const int* __restrict__ dst,
                                const float* __restrict__ f, const float* __restrict__ trans,
                                const float* __restrict__ normf, const float* __restrict__ normt,
                                unsigned* __restrict__ mask, int* __restrict__ cnt,
                                int nE, int nN)
{
  const int lane = threadIdx.x & 63;
  const int wib  = threadIdx.x >> 6;
  const int wpb  = blockDim.x >> 6;
  for (int e = blockIdx.x * wpb + wib; e < nE; e += gridDim.x * wpb) {
    const int s = src[e], d = dst[e];
    const float fd = f[d * FDIM + lane];
    float d0 = f[s * FDIM + lane] * fd;
    float d1 = trans[(0 * nN + s) * FDIM + lane] * fd;
    float d2 = trans[(1 * nN + s) * FDIM + lane] * fd;
    float d3 = trans[(2 * nN + s) * FDIM + lane] * fd;
#pragma unroll
    for (int o = 32; o > 0; o >>= 1) {
      d0 += __shfl_xor(d0, o);
      d1 += __shfl_xor(d1, o);
      d2 += __shfl_xor(d2, o);
      d3 += __shfl_xor(d3, o);
    }
    if (lane == 0) {
      const float nf = normf[s];
      unsigned m = 0;
      if (d1 * nf > d0 * normt[0 * nN + s]) m |= 1u;
      if (d2 * nf > d0 * normt[1 * nN + s]) m |= 2u;
      if (d3 * nf > d0 * normt[2 * nN + s]) m |= 4u;
      mask[e] = m;
      atomicAdd(&cnt[d], 1);
      if (m & 1u) atomicAdd(&cnt[nN + d], 1);
      if (m & 2u) atomicAdd(&cnt[2 * nN + d], 1);
      if (m & 4u) atomicAdd(&cnt[3 * nN + d], 1);
    }
  }
}

// ---------- dinv from int counts ----------
__global__ void dinv_k(const int* __restrict__ cnt, float* __restrict__ dinv, int nN)
{
  int i = blockIdx.x * blockDim.x + threadIdx.x;
  int tot = 4 * nN;
  if (i < tot) {
    float base = (i < nN) ? 1.f : 2.f;  // block0: +self ; replicas: +identity edge +self
    dinv[i] = 1.f / sqrtf((float)cnt[i] + base);
  }
}

// ---------- exclusive prefix scan over block-0 counts (single block) ----------
__global__ void scan_k(const int* __restrict__ cnt, int* __restrict__ rowoff,
                       int* __restrict__ cursor, int nN)
{
  __shared__ int s[256];
  const int chunk = (nN + 255) / 256;
  const int lo = threadIdx.x * chunk;
  const int hi = min(lo + chunk, nN);
  int sum = 0;
  for (int i = lo; i < hi; ++i) sum += cnt[i];
  s[threadIdx.x] = sum;
  __syncthreads();
  if (threadIdx.x == 0) {
    int run = 0;
    for (int i = 0; i < 256; ++i) { int t = s[i]; s[i] = run; run += t; }
    rowoff[nN] = run;
  }
  __syncthreads();
  int run = s[threadIdx.x];
  for (int i = lo; i < hi; ++i) {
    rowoff[i] = run;
    cursor[i] = run;
    run += cnt[i];
  }
}

// ---------- CSR fill: csr[slot] = src | (mask<<20) ----------
__global__ void csr_fill_k(const int* __restrict__ src, const int* __restrict__ dst,
                           const unsigned* __restrict__ mask, int* __restrict__ cursor,
                           unsigned* __restrict__ csr, int nE)
{
  for (int e = blockIdx.x * blockDim.x + threadIdx.x; e < nE;
       e += gridDim.x * blockDim.x) {
    int d = dst[e];
    int pos = atomicAdd(&cursor[d], 1);
    csr[pos] = (unsigned)src[e] | (mask[e] << 20);
  }
}

// ---------- row scale: out[i,:] = in[i,:] * dinv[i] ----------
__global__ void scale_k(const float* __restrict__ in, const float* __restrict__ dinv,
                        float* __restrict__ out, int rows)
{
  int idx = blockIdx.x * blockDim.x + threadIdx.x;
  int tot = rows * FDIM;
  if (idx < tot) out[idx] = in[idx] * dinv[idx >> 6];
}

// ---------- fused CSR gather + GCN finish ----------
// One wave per destination node d. Accumulates all 4 block rows.
// xws: N rows = xw(block0) * dinv0 (pre-scaled message table)
// xw : unscaled; N rows (L0, input tiled) or 4N rows (L1) -- self-loop terms
// out rows: d (blk0) and t*nN+d:
//   blk0: ((a0 + xws[d]) * di0) + b
//   blkt: ((at + xws[d] + self*dit) * dit) + b,  self = xw[d] (L0) or xw[t*nN+d] (L1)
template<bool L0, bool RELU>
__global__ void gather_finish_k(const int* __restrict__ rowoff, const unsigned* __restrict__ csr,
                                const float* __restrict__ xws, const float* __restrict__ xw,
                                const float* __restrict__ dinv, const float* __restrict__ bias,
                                float* __restrict__ out, int nN)
{
  const int lane = threadIdx.x & 63;
  const int wib  = threadIdx.x >> 6;
  const int wpb  = blockDim.x >> 6;
  const float b = bias[lane];
  for (int d = blockIdx.x * wpb + wib; d < nN; d += gridDim.x * wpb) {
    const int start = rowoff[d], end = rowoff[d + 1];
    float a0 = 0.f, a1 = 0.f, a2 = 0.f, a3 = 0.f;
    for (int base = start; base < end; base += 64) {
      const int nrem = end - base;
      unsigned p = (lane < nrem) ? csr[base + lane] : 0u;
      const int cntj = nrem < 64 ? nrem : 64;
      for (int j = 0; j < cntj; ++j) {
        const unsigned pj = (unsigned)__shfl((int)p, j);
        const int s = (int)(pj & 0xFFFFFu);
        const unsigned mk = pj >> 20;
        const float v = xws[s * FDIM + lane];
        a0 += v;
        if (mk & 1u) a1 += v;
        if (mk & 2u) a2 += v;
        if (mk & 4u) a3 += v;
      }
    }
    const float di0 = dinv[d];
    const float xs  = xws[d * FDIM + lane];
    const float xb0 = xw[d * FDIM + lane];

    float r0 = (a0 + xs) * di0 + b;
    if (RELU) r0 = fmaxf(r0, 0.f);
    out[d * FDIM + lane] = r0;

#pragma unroll
    for (int t = 1; t <= 3; ++t) {
      const float at = (t == 1) ? a1 : (t == 2) ? a2 : a3;
      const float dit = dinv[t * nN + d];
      const float self = L0 ? xb0 : xw[((size_t)t * nN + d) * FDIM + lane];
      float r = (at + xs + self * dit) * dit + b;
      if (RELU) r = fmaxf(r, 0.f);
      out[((size_t)t * nN + d) * FDIM + lane] = r;
    }
  }
}

// ---------- logits + argmax + H accumulation ----------
__global__ void logits_argmax_k(const float* __restrict__ x2, const float* __restrict__ W,
                                const float* __restrict__ bias, float* __restrict__ H,
                                int nN)
{
  __shared__ float Wl[FDIM * NSDIM];
  for (int i = threadIdx.x; i < FDIM * NSDIM; i += blockDim.x) Wl[i] = W[i];
  __syncthreads();
  const int lane = threadIdx.x & 63;
  const int wib  = threadIdx.x >> 6;
  const int wpb  = blockDim.x >> 6;
  const int rows = 4 * nN;
  for (int row = blockIdx.x * wpb + wib; row < rows; row += gridDim.x * wpb) {
    float h = fmaxf(x2[row * FDIM + lane], 0.f);
    float acc = bias[lane];
#pragma unroll
    for (int k = 0; k < FDIM; ++k)
      acc = fmaf(__shfl(h, k), Wl[k * NSDIM + lane], acc);
    float bv = acc; int bi = lane;
#pragma unroll
    for (int o = 32; o > 0; o >>= 1) {
      float ov = __shfl_xor(bv, o);
      int   oi = __shfl_xor(bi, o);
      if (ov > bv || (ov == bv && oi < bi)) { bv = ov; bi = oi; }
    }
    if (lane == 0) {
      int v = row % nN;
      atomicAdd(&H[v * NSDIM + bi], 1.f);
    }
  }
}

// ---------- hyper[j,:] += x2_b0[i,:] where H[i,j] > 0 (LDS-accumulated) ----------
__global__ void hyper_k(const float* __restrict__ H, const float* __restrict__ x2,
                        float* __restrict__ hyper, int nN)
{
  __shared__ float hl[NSDIM * FDIM];
  for (int i = threadIdx.x; i < NSDIM * FDIM; i += blockDim.x) hl[i] = 0.f;
  __syncthreads();
  const int lane = threadIdx.x & 63;
  const int wib  = threadIdx.x >> 6;
  const int wpb  = blockDim.x >> 6;
  for (int i = blockIdx.x * wpb + wib; i < nN; i += gridDim.x * wpb) {
    float hv = H[i * NSDIM + lane];
    unsigned long long ball = __ballot(hv > 0.f);
    float x = x2[i * FDIM + lane];
    while (ball) {
      int j = __ffsll((unsigned long long)ball) - 1;
      ball &= ball - 1;
      atomicAdd(&hl[j * FDIM + lane], x);
    }
  }
  __syncthreads();
  for (int i = threadIdx.x; i < NSDIM * FDIM; i += blockDim.x) {
    float v = hl[i];
    if (v != 0.f) atomicAdd(&hyper[i], v);
  }
}

__global__ void copy_k(const float* __restrict__ in, float* __restrict__ out, int n)
{
  int i = blockIdx.x * blockDim.x + threadIdx.x;
  if (i < n) out[i] = in[i];
}

// ---------- per-column histogram -> max + softmax denominator (H in {0..4}) ----------
__global__ void colstats_k(const float* __restrict__ H, float* __restrict__ cmax,
                           float* __restrict__ cden, int nN)
{
  __shared__ int s[8];
  const int j = blockIdx.x;
  if (threadIdx.x < 8) s[threadIdx.x] = 0;
  __syncthreads();
  int c[5] = {0, 0, 0, 0, 0};
  for (int i = threadIdx.x; i < nN; i += blockDim.x) {
    int v = (int)H[i * NSDIM + j];
    c[v]++;
  }
#pragma unroll
  for (int k = 0; k < 5; ++k) atomicAdd(&s[k], c[k]);
  __syncthreads();
  if (threadIdx.x == 0) {
    int m = 0;
#pragma unroll
    for (int k = 0; k < 5; ++k) if (s[k] > 0) m = k;
    float den = 0.f;
#pragma unroll
    for (int k = 0; k < 5; ++k) den += (float)s[k] * expf((float)(k - m));
    cmax[j] = (float)m;
    cden[j] = den;
  }
}

__global__ void hsoft_k(const float* __restrict__ H, const float* __restrict__ cmax,
                        const float* __restrict__ cden, float* __restrict__ out0, int nN)
{
  int idx = blockIdx.x * blockDim.x + threadIdx.x;
  int tot = nN * NSDIM;
  if (idx < tot) {
    int j = idx & (NSDIM - 1);
    out0[idx] = expf(H[idx] - cmax[j]) / cden[j];
  }
}

// ---------- dots = (features @ hyper^T) * 0.125, tiled 4x ----------
__global__ void dots_k(const float* __restrict__ f, const float* __restrict__ hyper,
                       float* __restrict__ out2, int nN)
{
  __shared__ float Ht[FDIM * NSDIM];
  for (int idx = threadIdx.x; idx < NSDIM * FDIM; idx += blockDim.x) {
    int j = idx / FDIM, k = idx - j * FDIM;
    Ht[k * NSDIM + j] = hyper[idx];
  }
  __syncthreads();
  const int lane = threadIdx.x & 63;
  const int wib  = threadIdx.x >> 6;
  const int wpb  = blockDim.x >> 6;
  for (int i = blockIdx.x * wpb + wib; i < nN; i += gridDim.x * wpb) {
    float fv = f[i * FDIM + lane];
    float acc = 0.f;
#pragma unroll
    for (int k = 0; k < FDIM; ++k)
      acc = fmaf(__shfl(fv, k), Ht[k * NSDIM + lane], acc);
    acc *= 0.125f;
#pragma unroll
    for (int b = 0; b < 4; ++b)
      out2[(b * nN + i) * NSDIM + lane] = acc;
  }
}

// ---------- host ----------
extern "C" void kernel_launch(void* const* d_in, const int* in_sizes, int n_in,
                              void* d_out, int out_size, void* d_ws, size_t ws_size,
                              hipStream_t stream)
{
  const int* edge_index = (const int*)d_in[0];
  const float* features = (const float*)d_in[1];
  const float* W_lin    = (const float*)d_in[2];
  const float* b_lin    = (const float*)d_in[3];
  const float* gcn0_W   = (const float*)d_in[4];
  const float* gcn0_b   = (const float*)d_in[5];
  const float* gcn1_W   = (const float*)d_in[6];
  const float* gcn1_b   = (const float*)d_in[7];
  const float* lin1_W   = (const float*)d_in[8];
  const float* lin1_b   = (const float*)d_in[9];

  const int E = in_sizes[0] / 2;
  const int N = in_sizes[1] / FDIM;

  const int* src = edge_index;
  const int* dst = edge_index + E;

  // workspace layout
  float* ws    = (float*)d_ws;
  float* trans = ws;                                   // T*N*F (dead after edge_mask)
  float* normf = trans + (size_t)TREP * N * FDIM;      // N
  float* normt = normf + N;                            // T*N
  int*   cnt   = (int*)(normt + (size_t)TREP * N);     // 4N int counts
  float* dinv  = (float*)(cnt + (size_t)4 * N);        // 4N
  unsigned* mask = (unsigned*)(dinv + (size_t)4 * N);  // E
  float* xw0   = (float*)(mask + E);                   // N*F
  float* bufA  = xw0 + (size_t)N * FDIM;               // 4N*F (x1 -> x2)
  float* bufB  = bufA + (size_t)4 * N * FDIM;          // 4N*F (xw1)
  float* Harr  = bufB + (size_t)4 * N * FDIM;          // N*NS
  float* hyper = Harr + (size_t)N * NSDIM;             // NS*F
  float* cmax  = hyper + NSDIM * FDIM;                 // NS
  float* cden  = cmax + NSDIM;                         // NS

  // alias CSR structures + scaled tables into the (dead-after-mask) trans region
  int* rowoff      = (int*)trans;                      // N+1
  int* cursor      = rowoff + (N + 1);                 // N
  unsigned* csr    = (unsigned*)(cursor + N);          // E
  float* xws       = (float*)(csr + E);                // N*F (scaled message table)
  // (N+1 + N + E + N*F) ints = ~16.4 MB < trans's 38.4 MB

  float* out0 = (float*)d_out;             // H_soft (N,NS)
  float* out1 = out0 + (size_t)N * NSDIM;  // hyper (NS,F)
  float* out2 = out1 + NSDIM * FDIM;       // dots (4N,NS)

  const int BLK = 256;
  const int WPB = BLK / 64;
  auto wgrid = [](int items, int wpb) { return (items + wpb - 1) / wpb; };

  // zero accumulators
  hipMemsetAsync(cnt, 0, (size_t)4 * N * sizeof(int), stream);
  hipMemsetAsync(Harr, 0, (size_t)N * NSDIM * sizeof(float), stream);
  hipMemsetAsync(hyper, 0, (size_t)NSDIM * FDIM * sizeof(float), stream);

  // 1) trans[t] = features @ W_lin[t] + b_lin[t]  (batched over gridDim.y)
  {
    dim3 g(wgrid(N, WPB), TREP);
    trans_gemm_k<<<g, BLK, 0, stream>>>(features, W_lin, b_lin, trans, N);
  }

  // 2) norms
  rownorm_k<<<wgrid(N, WPB), BLK, 0, stream>>>(features, normf, N);
  rownorm_k<<<wgrid(TREP * N, WPB), BLK, 0, stream>>>(trans, normt, TREP * N);

  // 3) edge mask + int degree counts
  edge_mask_cnt_k<<<wgrid(E, WPB), BLK, 0, stream>>>(src, dst, features, trans,
                                                     normf, normt, mask, cnt, E, N);

  // 4) CSR build (trans is dead now; rowoff/cursor/csr/xws alias it)
  scan_k<<<1, 256, 0, stream>>>(cnt, rowoff, cursor, N);
  csr_fill_k<<<1024, BLK, 0, stream>>>(src, dst, mask, cursor, csr, E);

  // 5) dinv
  dinv_k<<<(4 * N + BLK - 1) / BLK, BLK, 0, stream>>>(cnt, dinv, N);

  // 6) xw0 = relu(features) @ gcn0_W ; xws = xw0 * dinv0
  rowgemm_k<true><<<wgrid(N, WPB), BLK, 0, stream>>>(features, gcn0_W, xw0, N);
  scale_k<<<(N * FDIM + BLK - 1) / BLK, BLK, 0, stream>>>(xw0, dinv, xws, N);

  // 7) gcn0 gather+finish -> x1 (relu'd) in bufA
  gather_finish_k<true, true><<<wgrid(N, WPB), BLK, 0, stream>>>(
      rowoff, csr, xws, xw0, dinv, gcn0_b, bufA, N);

  // 8) xw1 = x1 @ gcn1_W (all 4N rows); xws = xw1(block0) * dinv0
  rowgemm_k<false><<<wgrid(4 * N, WPB), BLK, 0, stream>>>(bufA, gcn1_W, bufB, 4 * N);
  scale_k<<<(N * FDIM + BLK - 1) / BLK, BLK, 0, stream>>>(bufB, dinv, xws, N);

  // 9) gcn1 gather+finish -> x2 in bufA (no relu)
  gather_finish_k<false, false><<<wgrid(N, WPB), BLK, 0, stream>>>(
      rowoff, csr, xws, bufB, dinv, gcn1_b, bufA, N);

  // 10) logits + argmax -> H counts
  logits_argmax_k<<<wgrid(4 * N, WPB), BLK, 0, stream>>>(bufA, lin1_W, lin1_b, Harr, N);

  // 11) hyper (LDS-accumulated)
  hyper_k<<<128, BLK, 0, stream>>>(Harr, bufA, hyper, N);
  copy_k<<<(NSDIM * FDIM + BLK - 1) / BLK, BLK, 0, stream>>>(hyper, out1, NSDIM * FDIM);

  // 12) H softmax over axis 0
  colstats_k<<<NSDIM, BLK, 0, stream>>>(Harr, cmax, cden, N);
  hsoft_k<<<(N * NSDIM + BLK - 1) / BLK, BLK, 0, stream>>>(Harr, cmax, cden, out0, N);

  // 13) dots
  dots_k<<<wgrid(N, WPB), BLK, 0, stream>>>(features, hyper, out2, N);
}

// Round 4
// 909.230 us; speedup vs baseline: 3.7848x; 1.8238x over previous
//
#include <hip/hip_runtime.h>

#define FDIM 64
#define NSDIM 64
#define TREP 3
#define EPSV 1e-8f

// ============================================================================
// Register-tile GEMM family: one lane owns one output row (64 f32 accumulators
// in VGPRs). X row loaded per-lane as float4 (VMEM); W rows read via wave-
// uniform pointers -> scalar loads (SGPR), so the inner loop is pure v_fmac
// with an SGPR operand. No LDS-pipe traffic at all.
// ============================================================================

// ---------- trans: out[t,r,:] = X[r,:] @ W[t] + b[t]; fused row norms ----------
__global__ __launch_bounds__(256) void trans_k(const float* __restrict__ X,
                                               const float* __restrict__ W,
                                               const float* __restrict__ B,
                                               float* __restrict__ out,
                                               float* __restrict__ normf,
                                               float* __restrict__ normt, int nN)
{
  const int t    = blockIdx.y;
  const int lane = threadIdx.x & 63;
  const int wib  = threadIdx.x >> 6;
  const int row  = blockIdx.x * 256 + wib * 64 + lane;
  const float* __restrict__ Wt = W + (size_t)t * FDIM * FDIM;
  const float* __restrict__ Bt = B + t * FDIM;
  float acc[FDIM];
#pragma unroll
  for (int c = 0; c < FDIM; ++c) acc[c] = Bt[c];
  if (row >= nN) return;
  const float4* __restrict__ xr = (const float4*)(X + (size_t)row * FDIM);
  float ss = 0.f;
#pragma unroll 2
  for (int kk = 0; kk < FDIM / 4; ++kk) {
    const float4 xv = xr[kk];
    ss = fmaf(xv.x, xv.x, fmaf(xv.y, xv.y, fmaf(xv.z, xv.z, fmaf(xv.w, xv.w, ss))));
    const float* __restrict__ w0 = Wt + (kk * 4 + 0) * FDIM;
    const float* __restrict__ w1 = Wt + (kk * 4 + 1) * FDIM;
    const float* __restrict__ w2 = Wt + (kk * 4 + 2) * FDIM;
    const float* __restrict__ w3 = Wt + (kk * 4 + 3) * FDIM;
#pragma unroll
    for (int c = 0; c < FDIM; ++c) acc[c] = fmaf(xv.x, w0[c], acc[c]);
#pragma unroll
    for (int c = 0; c < FDIM; ++c) acc[c] = fmaf(xv.y, w1[c], acc[c]);
#pragma unroll
    for (int c = 0; c < FDIM; ++c) acc[c] = fmaf(xv.z, w2[c], acc[c]);
#pragma unroll
    for (int c = 0; c < FDIM; ++c) acc[c] = fmaf(xv.w, w3[c], acc[c]);
  }
  float* __restrict__ orow = out + ((size_t)t * nN + row) * FDIM;
  float sq = 0.f;
#pragma unroll
  for (int c4 = 0; c4 < FDIM / 4; ++c4) {
    float4 v = make_float4(acc[4 * c4], acc[4 * c4 + 1], acc[4 * c4 + 2], acc[4 * c4 + 3]);
    sq = fmaf(v.x, v.x, fmaf(v.y, v.y, fmaf(v.z, v.z, fmaf(v.w, v.w, sq))));
    ((float4*)orow)[c4] = v;
  }
  normt[t * nN + row] = fmaxf(sqrtf(sq), EPSV);
  if (t == 0) normf[row] = fmaxf(sqrtf(ss), EPSV);
}

// ---------- generic: out[r,:] = act(X[r,:]) @ W ; fused scaled copy ----------
template<bool RELU_IN>
__global__ __launch_bounds__(256) void gemm_k(const float* __restrict__ X,
                                              const float* __restrict__ W,
                                              float* __restrict__ out, int rows,
                                              float* __restrict__ scaled,
                                              const float* __restrict__ dinv, int nScaled)
{
  const int lane = threadIdx.x & 63;
  const int wib  = threadIdx.x >> 6;
  const int row  = blockIdx.x * 256 + wib * 64 + lane;
  if (row >= rows) return;
  float acc[FDIM];
#pragma unroll
  for (int c = 0; c < FDIM; ++c) acc[c] = 0.f;
  const float4* __restrict__ xr = (const float4*)(X + (size_t)row * FDIM);
#pragma unroll 2
  for (int kk = 0; kk < FDIM / 4; ++kk) {
    float4 xv = xr[kk];
    if (RELU_IN) {
      xv.x = fmaxf(xv.x, 0.f); xv.y = fmaxf(xv.y, 0.f);
      xv.z = fmaxf(xv.z, 0.f); xv.w = fmaxf(xv.w, 0.f);
    }
    const float* __restrict__ w0 = W + (kk * 4 + 0) * FDIM;
    const float* __restrict__ w1 = W + (kk * 4 + 1) * FDIM;
    const float* __restrict__ w2 = W + (kk * 4 + 2) * FDIM;
    const float* __restrict__ w3 = W + (kk * 4 + 3) * FDIM;
#pragma unroll
    for (int c = 0; c < FDIM; ++c) acc[c] = fmaf(xv.x, w0[c], acc[c]);
#pragma unroll
    for (int c = 0; c < FDIM; ++c) acc[c] = fmaf(xv.y, w1[c], acc[c]);
#pragma unroll
    for (int c = 0; c < FDIM; ++c) acc[c] = fmaf(xv.z, w2[c], acc[c]);
#pragma unroll
    for (int c = 0; c < FDIM; ++c) acc[c] = fmaf(xv.w, w3[c], acc[c]);
  }
  float* __restrict__ orow = out + (size_t)row * FDIM;
#pragma unroll
  for (int c4 = 0; c4 < FDIM / 4; ++c4)
    ((float4*)orow)[c4] = make_float4(acc[4 * c4], acc[4 * c4 + 1],
                                      acc[4 * c4 + 2], acc[4 * c4 + 3]);
  if (scaled != nullptr && row < nScaled) {
    const float dv = dinv[row];
    float* __restrict__ srow = scaled + (size_t)row * FDIM;
#pragma unroll
    for (int c4 = 0; c4 < FDIM / 4; ++c4)
      ((float4*)srow)[c4] = make_float4(acc[4 * c4] * dv, acc[4 * c4 + 1] * dv,
                                        acc[4 * c4 + 2] * dv, acc[4 * c4 + 3] * dv);
  }
}

// ---------- logits + per-lane argmax + H count ----------
__global__ __launch_bounds__(256) void logits_k(const float* __restrict__ X,
                                                const float* __restrict__ W,
                                                const float* __restrict__ B,
                                                float* __restrict__ H,
                                                int rows, int nN)
{
  const int lane = threadIdx.x & 63;
  const int wib  = threadIdx.x >> 6;
  const int row  = blockIdx.x * 256 + wib * 64 + lane;
  float acc[NSDIM];
#pragma unroll
  for (int c = 0; c < NSDIM; ++c) acc[c] = B[c];
  if (row >= rows) return;
  const float4* __restrict__ xr = (const float4*)(X + (size_t)row * FDIM);
#pragma unroll 2
  for (int kk = 0; kk < FDIM / 4; ++kk) {
    float4 xv = xr[kk];
    xv.x = fmaxf(xv.x, 0.f); xv.y = fmaxf(xv.y, 0.f);
    xv.z = fmaxf(xv.z, 0.f); xv.w = fmaxf(xv.w, 0.f);
    const float* __restrict__ w0 = W + (kk * 4 + 0) * NSDIM;
    const float* __restrict__ w1 = W + (kk * 4 + 1) * NSDIM;
    const float* __restrict__ w2 = W + (kk * 4 + 2) * NSDIM;
    const float* __restrict__ w3 = W + (kk * 4 + 3) * NSDIM;
#pragma unroll
    for (int c = 0; c < NSDIM; ++c) acc[c] = fmaf(xv.x, w0[c], acc[c]);
#pragma unroll
    for (int c = 0; c < NSDIM; ++c) acc[c] = fmaf(xv.y, w1[c], acc[c]);
#pragma unroll
    for (int c = 0; c < NSDIM; ++c) acc[c] = fmaf(xv.z, w2[c], acc[c]);
#pragma unroll
    for (int c = 0; c < NSDIM; ++c) acc[c] = fmaf(xv.w, w3[c], acc[c]);
  }
  float bv = acc[0]; int bi = 0;
#pragma unroll
  for (int c = 1; c < NSDIM; ++c)
    if (acc[c] > bv) { bv = acc[c]; bi = c; }   // strict > : first-index tiebreak
  int v = row;
  while (v >= nN) v -= nN;   // at most 3 iterations
  atomicAdd(&H[(size_t)v * NSDIM + bi], 1.f);
}

// ---------- dots = (features @ hyperT) * 0.125, tiled 4x ----------
__global__ __launch_bounds__(256) void dots_k(const float* __restrict__ X,
                                              const float* __restrict__ WT,
                                              float* __restrict__ out2, int nN)
{
  const int lane = threadIdx.x & 63;
  const int wib  = threadIdx.x >> 6;
  const int row  = blockIdx.x * 256 + wib * 64 + lane;
  if (row >= nN) return;
  float acc[NSDIM];
#pragma unroll
  for (int c = 0; c < NSDIM; ++c) acc[c] = 0.f;
  const float4* __restrict__ xr = (const float4*)(X + (size_t)row * FDIM);
#pragma unroll 2
  for (int kk = 0; kk < FDIM / 4; ++kk) {
    const float4 xv = xr[kk];
    const float* __restrict__ w0 = WT + (kk * 4 + 0) * NSDIM;
    const float* __restrict__ w1 = WT + (kk * 4 + 1) * NSDIM;
    const float* __restrict__ w2 = WT + (kk * 4 + 2) * NSDIM;
    const float* __restrict__ w3 = WT + (kk * 4 + 3) * NSDIM;
#pragma unroll
    for (int c = 0; c < NSDIM; ++c) acc[c] = fmaf(xv.x, w0[c], acc[c]);
#pragma unroll
    for (int c = 0; c < NSDIM; ++c) acc[c] = fmaf(xv.y, w1[c], acc[c]);
#pragma unroll
    for (int c = 0; c < NSDIM; ++c) acc[c] = fmaf(xv.z, w2[c], acc[c]);
#pragma unroll
    for (int c = 0; c < NSDIM; ++c) acc[c] = fmaf(xv.w, w3[c], acc[c]);
  }
#pragma unroll
  for (int c = 0; c < NSDIM; ++c) acc[c] *= 0.125f;
#pragma unroll
  for (int b = 0; b < 4; ++b) {
    float* __restrict__ orow = out2 + ((size_t)b * nN + row) * NSDIM;
#pragma unroll
    for (int c4 = 0; c4 < NSDIM / 4; ++c4)
      ((float4*)orow)[c4] = make_float4(acc[4 * c4], acc[4 * c4 + 1],
                                        acc[4 * c4 + 2], acc[4 * c4 + 3]);
  }
}

// ============================================================================
// Edge / graph kernels
// ============================================================================

// ---------- per-edge mask + int degree counts (wave per edge) ----------
__global__ void edge_mask_cnt_k(const int* __restrict__ src, const int* __restrict__ dst,
                                const float* __restrict__ f, const float* __restrict__ trans,
                                const float* __restrict__ normf, const float* __restrict__ normt,
                                unsigned* __restrict__ mask, int* __restrict__ cnt,
                                int nE, int nN)
{
  const int lane = threadIdx.x & 63;
  const int wib  = threadIdx.x >> 6;
  const int wpb  = blockDim.x >> 6;
  for (int e = blockIdx.x * wpb + wib; e < nE; e += gridDim.x * wpb) {
    const int s = src[e], d = dst[e];
    const float fd = f[d * FDIM + lane];
    float d0 = f[s * FDIM + lane] * fd;
    float d1 = trans[(0 * (size_t)nN + s) * FDIM + lane] * fd;
    float d2 = trans[(1 * (size_t)nN + s) * FDIM + lane] * fd;
    float d3 = trans[(2 * (size_t)nN + s) * FDIM + lane] * fd;
#pragma unroll
    for (int o = 32; o > 0; o >>= 1) {
      d0 += __shfl_xor(d0, o);
      d1 += __shfl_xor(d1, o);
      d2 += __shfl_xor(d2, o);
      d3 += __shfl_xor(d3, o);
    }
    if (lane == 0) {
      const float nf = normf[s];
      unsigned m = 0;
      if (d1 * nf > d0 * normt[0 * (size_t)nN + s]) m |= 1u;
      if (d2 * nf > d0 * normt[1 * (size_t)nN + s]) m |= 2u;
      if (d3 * nf > d0 * normt[2 * (size_t)nN + s]) m |= 4u;
      mask[e] = m;
      atomicAdd(&cnt[d], 1);
      if (m & 1u) atomicAdd(&cnt[nN + d], 1);
      if (m & 2u) atomicAdd(&cnt[2 * nN + d], 1);
      if (m & 4u) atomicAdd(&cnt[3 * nN + d], 1);
    }
  }
}

// ---------- dinv from int counts ----------
__global__ void dinv_k(const int* __restrict__ cnt, float* __restrict__ dinv, int nN)
{
  int i = blockIdx.x * blockDim.x + threadIdx.x;
  int tot = 4 * nN;
  if (i < tot) {
    float base = (i < nN) ? 1.f : 2.f;  // block0: +self ; replicas: +identity edge +self
    dinv[i] = 1.f / sqrtf((float)cnt[i] + base);
  }
}

// ---------- exclusive prefix scan over block-0 counts (single block) ----------
__global__ void scan_k(const int* __restrict__ cnt, int* __restrict__ rowoff,
                       int* __restrict__ cursor, int nN)
{
  __shared__ int s[256];
  const int chunk = (nN + 255) / 256;
  const int lo = threadIdx.x * chunk;
  const int hi = min(lo + chunk, nN);
  int sum = 0;
  for (int i = lo; i < hi; ++i) sum += cnt[i];
  s[threadIdx.x] = sum;
  __syncthreads();
  if (threadIdx.x == 0) {
    int run = 0;
    for (int i = 0; i < 256; ++i) { int t = s[i]; s[i] = run; run += t; }
    rowoff[nN] = run;
  }
  __syncthreads();
  int run = s[threadIdx.x];
  for (int i = lo; i < hi; ++i) {
    rowoff[i] = run;
    cursor[i] = run;
    run += cnt[i];
  }
}

// ---------- CSR fill: csr[slot] = src | (mask<<20) ----------
__global__ void csr_fill_k(const int* __restrict__ src, const int* __restrict__ dst,
                           const unsigned* __restrict__ mask, int* __restrict__ cursor,
                           unsigned* __restrict__ csr, int nE)
{
  for (int e = blockIdx.x * blockDim.x + threadIdx.x; e < nE;
       e += gridDim.x * blockDim.x) {
    int d = dst[e];
    int pos = atomicAdd(&cursor[d], 1);
    csr[pos] = (unsigned)src[e] | (mask[e] << 20);
  }
}

// ---------- fused CSR gather + GCN finish (wave per destination node) ----------
template<bool L0, bool RELU>
__global__ void gather_finish_k(const int* __restrict__ rowoff, const unsigned* __restrict__ csr,
                                const float* __restrict__ xws, const float* __restrict__ xw,
                                const float* __restrict__ dinv, const float* __restrict__ bias,
                                float* __restrict__ out, int nN)
{
  const int lane = threadIdx.x & 63;
  const int wib  = threadIdx.x >> 6;
  const int wpb  = blockDim.x >> 6;
  const float b = bias[lane];
  for (int d = blockIdx.x * wpb + wib; d < nN; d += gridDim.x * wpb) {
    const int start = rowoff[d], end = rowoff[d + 1];
    float a0 = 0.f, a1 = 0.f, a2 = 0.f, a3 = 0.f;
    for (int base = start; base < end; base += 64) {
      const int nrem = end - base;
      unsigned p = (lane < nrem) ? csr[base + lane] : 0u;
      const int cntj = nrem < 64 ? nrem : 64;
      for (int j = 0; j < cntj; ++j) {
        const unsigned pj = (unsigned)__shfl((int)p, j);
        const int s = (int)(pj & 0xFFFFFu);
        const unsigned mk = pj >> 20;
        const float v = xws[(size_t)s * FDIM + lane];
        a0 += v;
        if (mk & 1u) a1 += v;
        if (mk & 2u) a2 += v;
        if (mk & 4u) a3 += v;
      }
    }
    const float di0 = dinv[d];
    const float xs  = xws[(size_t)d * FDIM + lane];
    const float xb0 = xw[(size_t)d * FDIM + lane];

    float r0 = (a0 + xs) * di0 + b;
    if (RELU) r0 = fmaxf(r0, 0.f);
    out[(size_t)d * FDIM + lane] = r0;

#pragma unroll
    for (int t = 1; t <= 3; ++t) {
      const float at = (t == 1) ? a1 : (t == 2) ? a2 : a3;
      const float dit = dinv[t * nN + d];
      const float self = L0 ? xb0 : xw[((size_t)t * nN + d) * FDIM + lane];
      float r = (at + xs + self * dit) * dit + b;
      if (RELU) r = fmaxf(r, 0.f);
      out[((size_t)t * nN + d) * FDIM + lane] = r;
    }
  }
}

// ---------- hyper[j,:] += x2_b0[i,:] where H[i,j] > 0 (LDS-accumulated) ----------
__global__ void hyper_k(const float* __restrict__ H, const float* __restrict__ x2,
                        float* __restrict__ hyper, int nN)
{
  __shared__ float hl[NSDIM * FDIM];
  for (int i = threadIdx.x; i < NSDIM * FDIM; i += blockDim.x) hl[i] = 0.f;
  __syncthreads();
  const int lane = threadIdx.x & 63;
  const int wib  = threadIdx.x >> 6;
  const int wpb  = blockDim.x >> 6;
  for (int i = blockIdx.x * wpb + wib; i < nN; i += gridDim.x * wpb) {
    float hv = H[(size_t)i * NSDIM + lane];
    unsigned long long ball = __ballot(hv > 0.f);
    float x = x2[(size_t)i * FDIM + lane];
    while (ball) {
      int j = __ffsll((unsigned long long)ball) - 1;
      ball &= ball - 1;
      atomicAdd(&hl[j * FDIM + lane], x);
    }
  }
  __syncthreads();
  for (int i = threadIdx.x; i < NSDIM * FDIM; i += blockDim.x) {
    float v = hl[i];
    if (v != 0.f) atomicAdd(&hyper[i], v);
  }
}

// ---------- hyper -> out1 + transposed copy for dots ----------
__global__ void hfin_k(const float* __restrict__ hyper, float* __restrict__ out1,
                       float* __restrict__ hyperT)
{
  int idx = blockIdx.x * blockDim.x + threadIdx.x;
  if (idx < NSDIM * FDIM) {
    float v = hyper[idx];
    out1[idx] = v;
    int j = idx >> 6, k = idx & 63;
    hyperT[k * NSDIM + j] = v;
  }
}

// ---------- per-column histogram -> max + softmax denominator (H in {0..4}) ----------
__global__ void colstats_k(const float* __restrict__ H, float* __restrict__ cmax,
                           float* __restrict__ cden, int nN)
{
  __shared__ int s[8];
  const int j = blockIdx.x;
  if (threadIdx.x < 8) s[threadIdx.x] = 0;
  __syncthreads();
  int c[5] = {0, 0, 0, 0, 0};
  for (int i = threadIdx.x; i < nN; i += blockDim.x) {
    int v = (int)H[(size_t)i * NSDIM + j];
    c[v]++;
  }
#pragma unroll
  for (int k = 0; k < 5; ++k) atomicAdd(&s[k], c[k]);
  __syncthreads();
  if (threadIdx.x == 0) {
    int m = 0;
#pragma unroll
    for (int k = 0; k < 5; ++k) if (s[k] > 0) m = k;
    float den = 0.f;
#pragma unroll
    for (int k = 0; k < 5; ++k) den += (float)s[k] * expf((float)(k - m));
    cmax[j] = (float)m;
    cden[j] = den;
  }
}

__global__ void hsoft_k(const float* __restrict__ H, const float* __restrict__ cmax,
                        const float* __restrict__ cden, float* __restrict__ out0, int nN)
{
  int idx = blockIdx.x * blockDim.x + threadIdx.x;
  int tot = nN * NSDIM;
  if (idx < tot) {
    int j = idx & (NSDIM - 1);
    out0[idx] = expf(H[idx] - cmax[j]) / cden[j];
  }
}

// ---------- host ----------
extern "C" void kernel_launch(void* const* d_in, const int* in_sizes, int n_in,
                              void* d_out, int out_size, void* d_ws, size_t ws_size,
                              hipStream_t stream)
{
  const int* edge_index = (const int*)d_in[0];
  const float* features = (const float*)d_in[1];
  const float* W_lin    = (const float*)d_in[2];
  const float* b_lin    = (const float*)d_in[3];
  const float* gcn0_W   = (const float*)d_in[4];
  const float* gcn0_b   = (const float*)d_in[5];
  const float* gcn1_W   = (const float*)d_in[6];
  const float* gcn1_b   = (const float*)d_in[7];
  const float* lin1_W   = (const float*)d_in[8];
  const float* lin1_b   = (const float*)d_in[9];

  const int E = in_sizes[0] / 2;
  const int N = in_sizes[1] / FDIM;

  const int* src = edge_index;
  const int* dst = edge_index + E;

  // workspace layout
  float* ws    = (float*)d_ws;
  float* trans = ws;                                   // T*N*F (dead after edge_mask)
  float* normf = trans + (size_t)TREP * N * FDIM;      // N
  float* normt = normf + N;                            // T*N
  int*   cnt   = (int*)(normt + (size_t)TREP * N);     // 4N int counts
  float* dinv  = (float*)(cnt + (size_t)4 * N);        // 4N
  unsigned* mask = (unsigned*)(dinv + (size_t)4 * N);  // E
  float* xw0   = (float*)(mask + E);                   // N*F
  float* bufA  = xw0 + (size_t)N * FDIM;               // 4N*F (x1 -> x2)
  float* bufB  = bufA + (size_t)4 * N * FDIM;          // 4N*F (xw1)
  float* Harr  = bufB + (size_t)4 * N * FDIM;          // N*NS
  float* hyper = Harr + (size_t)N * NSDIM;             // NS*F
  float* cmax  = hyper + NSDIM * FDIM;                 // NS
  float* cden  = cmax + NSDIM;                         // NS
  float* hyperT = cden + NSDIM;                        // NS*F (transposed)

  // alias CSR structures + scaled message table into the dead trans region
  // (rowoff padded to N+64 ints to keep xws 16B-aligned)
  int* rowoff      = (int*)trans;                      // N+1 (padded N+64)
  int* cursor      = rowoff + (N + 64);                // N
  unsigned* csr    = (unsigned*)(cursor + N);          // E
  float* xws       = (float*)(csr + E);                // N*F scaled message table

  float* out0 = (float*)d_out;             // H_soft (N,NS)
  float* out1 = out0 + (size_t)N * NSDIM;  // hyper (NS,F)
  float* out2 = out1 + NSDIM * FDIM;       // dots (4N,NS)

  const int BLK = 256;
  const int WPB = BLK / 64;
  auto wgrid = [](int items, int wpb) { return (items + wpb - 1) / wpb; };
  auto tgrid = [](int rows) { return (rows + 255) / 256; };

  // zero accumulators
  hipMemsetAsync(cnt, 0, (size_t)4 * N * sizeof(int), stream);
  hipMemsetAsync(Harr, 0, (size_t)N * NSDIM * sizeof(float), stream);
  hipMemsetAsync(hyper, 0, (size_t)NSDIM * FDIM * sizeof(float), stream);

  // 1) trans[t] = features @ W_lin[t] + b_lin[t]  + fused normf/normt
  {
    dim3 g(tgrid(N), TREP);
    trans_k<<<g, BLK, 0, stream>>>(features, W_lin, b_lin, trans, normf, normt, N);
  }

  // 2) edge mask + int degree counts
  edge_mask_cnt_k<<<wgrid(E, WPB), BLK, 0, stream>>>(src, dst, features, trans,
                                                     normf, normt, mask, cnt, E, N);

  // 3) CSR build (trans dead; rowoff/cursor/csr/xws alias it)
  scan_k<<<1, 256, 0, stream>>>(cnt, rowoff, cursor, N);
  csr_fill_k<<<1024, BLK, 0, stream>>>(src, dst, mask, cursor, csr, E);

  // 4) dinv
  dinv_k<<<(4 * N + BLK - 1) / BLK, BLK, 0, stream>>>(cnt, dinv, N);

  // 5) xw0 = relu(features) @ gcn0_W ; fused xws = xw0 * dinv0
  gemm_k<true><<<tgrid(N), BLK, 0, stream>>>(features, gcn0_W, xw0, N, xws, dinv, N);

  // 6) gcn0 gather+finish -> x1 (relu'd) in bufA
  gather_finish_k<true, true><<<wgrid(N, WPB), BLK, 0, stream>>>(
      rowoff, csr, xws, xw0, dinv, gcn0_b, bufA, N);

  // 7) xw1 = x1 @ gcn1_W (4N rows); fused xws = xw1(block0) * dinv0
  gemm_k<false><<<tgrid(4 * N), BLK, 0, stream>>>(bufA, gcn1_W, bufB, 4 * N, xws, dinv, N);

  // 8) gcn1 gather+finish -> x2 in bufA (no relu)
  gather_finish_k<false, false><<<wgrid(N, WPB), BLK, 0, stream>>>(
      rowoff, csr, xws, bufB, dinv, gcn1_b, bufA, N);

  // 9) logits + argmax -> H counts
  logits_k<<<tgrid(4 * N), BLK, 0, stream>>>(bufA, lin1_W, lin1_b, Harr, 4 * N, N);

  // 10) hyper (LDS-accumulated) + out1 + transpose
  hyper_k<<<128, BLK, 0, stream>>>(Harr, bufA, hyper, N);
  hfin_k<<<(NSDIM * FDIM + BLK - 1) / BLK, BLK, 0, stream>>>(hyper, out1, hyperT);

  // 11) H softmax over axis 0
  colstats_k<<<NSDIM, BLK, 0, stream>>>(Harr, cmax, cden, N);
  hsoft_k<<<(N * NSDIM + BLK - 1) / BLK, BLK, 0, stream>>>(Harr, cmax, cden, out0, N);

  // 12) dots
  dots_k<<<tgrid(N), BLK, 0, stream>>>(features, hyperT, out2, N);
}